// Round 4
// baseline (503.486 us; speedup 1.0000x reference)
//
#include <hip/hip_runtime.h>

#define N_NODES   20000
#define N_EDGES   200000
#define NODE_DIM  32
#define EDGE_DIM  16
#define HIDDEN    32
#define N_GRAPHS  64
#define T_NODES   15   // src nodes per block; LDS = 15*1024*4 + 15*32*4*2 = 65280 B <= 64KB

// ===========================================================================
// CSR build (tgt-CSR positions + src-CSR edge lists, fused passes)
// ===========================================================================

__global__ __launch_bounds__(256) void build_deg2_kernel(
    const int* __restrict__ tgts, const int* __restrict__ srcs,
    int* __restrict__ deg_t, int* __restrict__ deg_s)
{
    int e = blockIdx.x * blockDim.x + threadIdx.x;
    if (e >= N_EDGES) return;
    atomicAdd(deg_t + tgts[e], 1);
    atomicAdd(deg_s + srcs[e], 1);
}

__device__ void chunked_scan(const int* __restrict__ deg, int* __restrict__ start,
                             int* __restrict__ cursor, int* partial)
{
    const int C = (N_NODES + 255) / 256;   // 79
    int t  = threadIdx.x;
    int lo = t * C;
    int hi = lo + C < N_NODES ? lo + C : N_NODES;
    int s = 0;
    for (int i = lo; i < hi; ++i) s += deg[i];
    partial[t] = s;
    __syncthreads();
    if (t == 0) {
        int run = 0;
        for (int i = 0; i < 256; ++i) { int v = partial[i]; partial[i] = run; run += v; }
    }
    __syncthreads();
    int run = partial[t];
    for (int i = lo; i < hi; ++i) {
        start[i]  = run;
        cursor[i] = run;
        run += deg[i];
    }
    if (lo < N_NODES && hi == N_NODES) start[N_NODES] = run;
    __syncthreads();
}

__global__ __launch_bounds__(256) void scan2_kernel(
    const int* __restrict__ deg_t, int* __restrict__ start_t, int* __restrict__ cur_t,
    const int* __restrict__ deg_s, int* __restrict__ start_s, int* __restrict__ cur_s)
{
    __shared__ int partial[256];
    chunked_scan(deg_t, start_t, cur_t, partial);
    chunked_scan(deg_s, start_s, cur_s, partial);
}

// pos_t[e] = slot of edge e in tgt-order (msg written there -> gather is streaming)
__global__ __launch_bounds__(256) void scatter2_kernel(
    const int* __restrict__ tgts, const int* __restrict__ srcs,
    int* __restrict__ cur_t, int* __restrict__ cur_s,
    int* __restrict__ pos_t, int* __restrict__ eid_s)
{
    int e = blockIdx.x * blockDim.x + threadIdx.x;
    if (e >= N_EDGES) return;
    int p1 = atomicAdd(cur_t + tgts[e], 1);
    pos_t[e] = p1;
    int p2 = atomicAdd(cur_s + srcs[e], 1);
    eid_s[p2] = e;
}

// ===========================================================================
// src_conv: per block, T_NODES src nodes.
// Phase A: P[t][k][o] = sum_i x[t][i]*W2[k][i*32+o]; Q[t][o] = sum_i x[t][i]*b2[i*32+o]
// Phase B: per out-edge: h_k = relu(b1+ea@W1) per lane-k,
//          msg[pos_t[e]][o] = Q[s][o] + sum_k shfl(h,k) * P[s][k][o]
// ===========================================================================
__global__ __launch_bounds__(256, 2) void src_conv_kernel(
    const float* __restrict__ feat,     // [N][32]
    const float* __restrict__ ea,       // [E][16]
    const int*   __restrict__ srcs,     // [E]
    const int*   __restrict__ start_s,  // [N+1]
    const int*   __restrict__ eid_s,    // [E]
    const int*   __restrict__ pos_t,    // [E]
    const float* __restrict__ W1,       // [16][32]
    const float* __restrict__ b1,       // [32]
    const float* __restrict__ W2,       // [32][1024]
    const float* __restrict__ b2,       // [1024]
    float*       __restrict__ msg)      // [E][32] in tgt-CSR order
{
    __shared__ float P[T_NODES][32][32];   // 61440 B
    __shared__ float Q[T_NODES][32];       //  1920 B
    __shared__ float XT[T_NODES][32];      //  1920 B

    int tid = threadIdx.x;
    int v0  = blockIdx.x * T_NODES;
    int T_act = (N_NODES - v0) < T_NODES ? (N_NODES - v0) : T_NODES;

    // ---- stage x tile into LDS (clamped for tail block) ----
    if (tid < 8 * T_NODES) {
        int t  = tid >> 3;
        int og = tid & 7;
        int vv = v0 + t; if (vv > N_NODES - 1) vv = N_NODES - 1;
        float4 xx = *reinterpret_cast<const float4*>(feat + (size_t)vv * 32 + og * 4);
        *reinterpret_cast<float4*>(&XT[t][og * 4]) = xx;
    }
    __syncthreads();

    // ---- Phase A: P tile ----
    {
        int og = tid & 7;     // o = og*4 + c
        int k  = tid >> 3;    // 0..31
        float acc[T_NODES][4];
        #pragma unroll
        for (int t = 0; t < T_NODES; ++t) {
            acc[t][0] = 0.f; acc[t][1] = 0.f; acc[t][2] = 0.f; acc[t][3] = 0.f;
        }
        const float* w2p = W2 + (size_t)k * 1024 + og * 4;
        #pragma unroll
        for (int i = 0; i < 32; ++i) {
            float4 w4 = *reinterpret_cast<const float4*>(w2p + i * 32);
            #pragma unroll
            for (int t = 0; t < T_NODES; ++t) {
                float xv = XT[t][i];
                acc[t][0] += xv * w4.x; acc[t][1] += xv * w4.y;
                acc[t][2] += xv * w4.z; acc[t][3] += xv * w4.w;
            }
        }
        #pragma unroll
        for (int t = 0; t < T_NODES; ++t) {
            float4 w; w.x = acc[t][0]; w.y = acc[t][1]; w.z = acc[t][2]; w.w = acc[t][3];
            *reinterpret_cast<float4*>(&P[t][k][og * 4]) = w;
        }
    }
    // ---- Q tile (threads 0..119) ----
    if (tid < 8 * T_NODES) {
        int t  = tid >> 3;
        int og = tid & 7;
        float q0 = 0.f, q1 = 0.f, q2 = 0.f, q3 = 0.f;
        const float* b2p = b2 + og * 4;
        #pragma unroll
        for (int i = 0; i < 32; ++i) {
            float4 b4 = *reinterpret_cast<const float4*>(b2p + i * 32);
            float xv = XT[t][i];
            q0 += xv * b4.x; q1 += xv * b4.y; q2 += xv * b4.z; q3 += xv * b4.w;
        }
        float4 qq; qq.x = q0; qq.y = q1; qq.z = q2; qq.w = q3;
        *reinterpret_cast<float4*>(&Q[t][og * 4]) = qq;
    }
    __syncthreads();

    // ---- Phase B: edges of this tile (contiguous src-CSR slice) ----
    int jb = start_s[v0];
    int je = start_s[v0 + T_act];
    int slot = tid >> 5;          // 0..7
    int kl   = tid & 31;          // lane's k (for h) and o (for output)
    int half = tid & 32;          // base lane of my 32-group within the wave

    float w1c[EDGE_DIM];
    #pragma unroll
    for (int j = 0; j < EDGE_DIM; ++j) w1c[j] = W1[j * 32 + kl];
    float b1v = b1[kl];

    for (int j0 = jb; j0 < je; j0 += 8) {
        int j = j0 + slot;
        if (j < je) {
            int e  = eid_s[j];
            int sl = srcs[e] - v0;
            int pr = pos_t[e];
            const float4* ea4 = reinterpret_cast<const float4*>(ea + (size_t)e * EDGE_DIM);
            float4 a0 = ea4[0], a1 = ea4[1], a2 = ea4[2], a3 = ea4[3];
            float hv = b1v;
            hv += a0.x * w1c[0]  + a0.y * w1c[1]  + a0.z * w1c[2]  + a0.w * w1c[3];
            hv += a1.x * w1c[4]  + a1.y * w1c[5]  + a1.z * w1c[6]  + a1.w * w1c[7];
            hv += a2.x * w1c[8]  + a2.y * w1c[9]  + a2.z * w1c[10] + a2.w * w1c[11];
            hv += a3.x * w1c[12] + a3.y * w1c[13] + a3.z * w1c[14] + a3.w * w1c[15];
            float h = fmaxf(hv, 0.f);

            float accv = Q[sl][kl];
            #pragma unroll
            for (int k = 0; k < 32; ++k) {
                float hk = __shfl(h, half + k, 64);
                accv += hk * P[sl][k][kl];
            }
            msg[(size_t)pr * 32 + kl] = accv;
        }
    }
}

// ===========================================================================
// gather_update: msg is already in tgt-CSR order -> pure streaming read.
// 32 lanes per node (lane o = channel o); + root GEMM + bias + relu;
// optional global mean-pool accumulation.
// ===========================================================================
__global__ __launch_bounds__(256) void gather_update_kernel(
    const float* __restrict__ feat,   // [N][32]
    const float* __restrict__ msg,    // [E][32] tgt-ordered
    const int*   __restrict__ start,  // [N+1] (tgt)
    const float* __restrict__ root,   // [32][32]
    const float* __restrict__ bias,   // [32]
    float*       __restrict__ outf,   // [N][32] or null
    const int*   __restrict__ batch,  // [N] or null
    float*       __restrict__ pool,   // [G][32]
    float*       __restrict__ pcnt)   // [G]
{
    int idx = blockIdx.x * blockDim.x + threadIdx.x;
    int v = idx >> 5;
    int o = idx & 31;
    if (v >= N_NODES) return;

    int s0 = start[v], s1 = start[v + 1];
    float sum = 0.0f;
    int j = s0;
    for (; j + 4 <= s1; j += 4) {
        float m0 = msg[(size_t)(j + 0) * 32 + o];
        float m1 = msg[(size_t)(j + 1) * 32 + o];
        float m2 = msg[(size_t)(j + 2) * 32 + o];
        float m3 = msg[(size_t)(j + 3) * 32 + o];
        sum += (m0 + m1) + (m2 + m3);
    }
    for (; j < s1; ++j) sum += msg[(size_t)j * 32 + o];

    int d = s1 - s0;
    float acc = sum / (float)(d > 0 ? d : 1) + bias[o];

    const float* xv = feat + (size_t)v * 32;
    #pragma unroll
    for (int i = 0; i < 32; ++i) acc += xv[i] * root[i * 32 + o];
    acc = fmaxf(acc, 0.0f);

    if (outf) outf[(size_t)v * 32 + o] = acc;
    if (batch) {
        int g = batch[v];
        atomicAdd(pool + (size_t)g * 32 + o, acc);
        if (o == 0) atomicAdd(pcnt + g, 1.0f);
    }
}

__global__ void head_kernel(
    const float* __restrict__ pool, const float* __restrict__ pcnt,
    const float* __restrict__ fcW, const float* __restrict__ fcb,
    float* __restrict__ out)
{
    int g = threadIdx.x;
    if (g >= N_GRAPHS) return;
    float inv = 1.0f / fmaxf(pcnt[g], 1.0f);
    float o0 = fcb[0], o1 = fcb[1];
    #pragma unroll
    for (int i = 0; i < 32; ++i) {
        float m = pool[g * 32 + i] * inv;
        o0 += m * fcW[i * 2 + 0];
        o1 += m * fcW[i * 2 + 1];
    }
    out[g * 2 + 0] = o0;
    out[g * 2 + 1] = o1;
}

// ===========================================================================
// Fallback (round-2 proven path): per-edge fused kernel, tgt-CSR only
// ===========================================================================
__global__ __launch_bounds__(256) void build_deg_kernel(
    const int* __restrict__ tgts, int* __restrict__ deg)
{
    int e = blockIdx.x * blockDim.x + threadIdx.x;
    if (e >= N_EDGES) return;
    atomicAdd(deg + tgts[e], 1);
}

__global__ __launch_bounds__(256) void scan_deg_kernel(
    const int* __restrict__ deg, int* __restrict__ start, int* __restrict__ cursor)
{
    __shared__ int partial[256];
    chunked_scan(deg, start, cursor, partial);
}

__global__ __launch_bounds__(256) void scatter_edges_kernel(
    const int* __restrict__ tgts, int* __restrict__ cursor, int* __restrict__ eid)
{
    int e = blockIdx.x * blockDim.x + threadIdx.x;
    if (e >= N_EDGES) return;
    int pos = atomicAdd(cursor + tgts[e], 1);
    eid[pos] = e;
}

__global__ __launch_bounds__(256) void edge_msg_kernel(
    const float* __restrict__ feat, const float* __restrict__ ea,
    const int* __restrict__ srcs,
    const float* __restrict__ W1, const float* __restrict__ b1,
    const float* __restrict__ W2, const float* __restrict__ b2,
    float* __restrict__ msg)
{
    int e = blockIdx.x * blockDim.x + threadIdx.x;
    if (e >= N_EDGES) return;
    float a[EDGE_DIM];
    const float4* ea4 = reinterpret_cast<const float4*>(ea + (size_t)e * EDGE_DIM);
    #pragma unroll
    for (int q = 0; q < EDGE_DIM / 4; ++q) {
        float4 t = ea4[q];
        a[q*4+0] = t.x; a[q*4+1] = t.y; a[q*4+2] = t.z; a[q*4+3] = t.w;
    }
    int s = srcs[e];
    float x[32];
    const float4* x4 = reinterpret_cast<const float4*>(feat + (size_t)s * 32);
    #pragma unroll
    for (int q = 0; q < 8; ++q) {
        float4 t = x4[q];
        x[q*4+0] = t.x; x[q*4+1] = t.y; x[q*4+2] = t.z; x[q*4+3] = t.w;
    }
    float acc[32];
    #pragma unroll
    for (int o = 0; o < 32; ++o) acc[o] = 0.0f;
    #pragma unroll
    for (int i = 0; i < 32; ++i) {
        float xi = x[i];
        #pragma unroll
        for (int o = 0; o < 32; ++o) acc[o] += xi * b2[i*32+o];
    }
    for (int k = 0; k < 32; ++k) {
        float hk = b1[k];
        #pragma unroll
        for (int j = 0; j < EDGE_DIM; ++j) hk += a[j] * W1[j*32 + k];
        hk = fmaxf(hk, 0.0f);
        const float* w = W2 + (size_t)k * 1024;
        #pragma unroll
        for (int i = 0; i < 32; ++i) {
            float c = hk * x[i];
            #pragma unroll
            for (int o = 0; o < 32; ++o) acc[o] += c * w[i*32+o];
        }
    }
    float4* m4 = reinterpret_cast<float4*>(msg + (size_t)e * 32);
    #pragma unroll
    for (int q = 0; q < 8; ++q) {
        float4 t;
        t.x = acc[q*4+0]; t.y = acc[q*4+1]; t.z = acc[q*4+2]; t.w = acc[q*4+3];
        m4[q] = t;
    }
}

// gather with eid indirection (fallback only)
__global__ __launch_bounds__(256) void gather_update_eid_kernel(
    const float* __restrict__ feat, const float* __restrict__ msg,
    const int* __restrict__ start, const int* __restrict__ eid,
    const float* __restrict__ root, const float* __restrict__ bias,
    float* __restrict__ outf, const int* __restrict__ batch,
    float* __restrict__ pool, float* __restrict__ pcnt)
{
    int idx = blockIdx.x * blockDim.x + threadIdx.x;
    int v = idx >> 5;
    int o = idx & 31;
    if (v >= N_NODES) return;
    int s0 = start[v], s1 = start[v + 1];
    float sum = 0.0f;
    for (int j = s0; j < s1; ++j) {
        int e = eid[j];
        sum += msg[(size_t)e * 32 + o];
    }
    int d = s1 - s0;
    float acc = sum / (float)(d > 0 ? d : 1) + bias[o];
    const float* xv = feat + (size_t)v * 32;
    #pragma unroll
    for (int i = 0; i < 32; ++i) acc += xv[i] * root[i * 32 + o];
    acc = fmaxf(acc, 0.0f);
    if (outf) outf[(size_t)v * 32 + o] = acc;
    if (batch) {
        int g = batch[v];
        atomicAdd(pool + (size_t)g * 32 + o, acc);
        if (o == 0) atomicAdd(pcnt + g, 1.0f);
    }
}

// ===========================================================================

extern "C" void kernel_launch(void* const* d_in, const int* in_sizes, int n_in,
                              void* d_out, int out_size, void* d_ws, size_t ws_size,
                              hipStream_t stream)
{
    const float* x      = (const float*)d_in[0];
    const float* ea     = (const float*)d_in[1];
    const int*   ei     = (const int*)d_in[2];   // [2][E]
    const int*   batch  = (const int*)d_in[3];
    const float* en1_W1 = (const float*)d_in[4];
    const float* en1_b1 = (const float*)d_in[5];
    const float* en1_W2 = (const float*)d_in[6];
    const float* en1_b2 = (const float*)d_in[7];
    const float* root1  = (const float*)d_in[8];
    const float* bias1  = (const float*)d_in[9];
    const float* en2_W1 = (const float*)d_in[10];
    const float* en2_b1 = (const float*)d_in[11];
    const float* en2_W2 = (const float*)d_in[12];
    const float* en2_b2 = (const float*)d_in[13];
    const float* root2  = (const float*)d_in[14];
    const float* bias2  = (const float*)d_in[15];
    const float* fcW    = (const float*)d_in[16];
    const float* fcb    = (const float*)d_in[17];

    const int* srcs = ei;
    const int* tgts = ei + N_EDGES;

    dim3 eb(256), eg((N_EDGES + 255) / 256);
    dim3 gb(256), gg((N_NODES * 32 + 255) / 256);
    const int NBLK = (N_NODES + T_NODES - 1) / T_NODES;

    // ---- new-path workspace layout (words) ----
    // zeroed: [deg_t N][deg_s N][pool G*32][pcnt G]
    // then:   [start_t N+2][cur_t N][pos_t E][start_s N+2][cur_s N][eid_s E]
    //         [msg E*32][h1 N*32]
    size_t need_new = (size_t)2*N_NODES + N_GRAPHS*32 + N_GRAPHS
                    + 2*(N_NODES + 2) + 2*N_NODES + 2*(size_t)N_EDGES
                    + (size_t)N_EDGES*32 + (size_t)N_NODES*32;
    size_t need_old = (size_t)N_NODES + N_GRAPHS*32 + N_GRAPHS
                    + (N_NODES + 1) + N_NODES + N_EDGES
                    + (size_t)N_EDGES*32 + (size_t)N_NODES*32;

    if (ws_size >= need_new * sizeof(float)) {
        int*   deg_t   = (int*)d_ws;
        int*   deg_s   = deg_t + N_NODES;
        float* pool    = (float*)(deg_s + N_NODES);
        float* pcnt    = pool + (size_t)N_GRAPHS*32;
        int*   start_t = (int*)(pcnt + N_GRAPHS);
        int*   cur_t   = start_t + (N_NODES + 2);
        int*   pos_t   = cur_t + N_NODES;
        int*   start_s = pos_t + N_EDGES;
        int*   cur_s   = start_s + (N_NODES + 2);
        int*   eid_s   = cur_s + N_NODES;
        float* msg     = (float*)(eid_s + N_EDGES);
        float* h1      = msg + (size_t)N_EDGES*32;
        size_t zeroBytes = ((size_t)2*N_NODES + N_GRAPHS*32 + N_GRAPHS) * sizeof(float);

        hipMemsetAsync(d_ws, 0, zeroBytes, stream);

        build_deg2_kernel<<<eg, eb, 0, stream>>>(tgts, srcs, deg_t, deg_s);
        scan2_kernel<<<dim3(1), dim3(256), 0, stream>>>(deg_t, start_t, cur_t,
                                                        deg_s, start_s, cur_s);
        scatter2_kernel<<<eg, eb, 0, stream>>>(tgts, srcs, cur_t, cur_s, pos_t, eid_s);

        // conv1
        src_conv_kernel<<<dim3(NBLK), dim3(256), 0, stream>>>(
            x, ea, srcs, start_s, eid_s, pos_t, en1_W1, en1_b1, en1_W2, en1_b2, msg);
        gather_update_kernel<<<gg, gb, 0, stream>>>(x, msg, start_t, root1, bias1,
                                                    h1, nullptr, nullptr, nullptr);
        // conv2
        src_conv_kernel<<<dim3(NBLK), dim3(256), 0, stream>>>(
            h1, ea, srcs, start_s, eid_s, pos_t, en2_W1, en2_b1, en2_W2, en2_b2, msg);
        gather_update_kernel<<<gg, gb, 0, stream>>>(h1, msg, start_t, root2, bias2,
                                                    nullptr, batch, pool, pcnt);

        head_kernel<<<dim3(1), dim3(64), 0, stream>>>(pool, pcnt, fcW, fcb, (float*)d_out);
    } else {
        // round-2 proven fallback (per-edge fused, tgt-CSR only)
        int*   deg    = (int*)d_ws;
        float* pool   = (float*)(deg + N_NODES);
        float* pcnt   = pool + (size_t)N_GRAPHS*32;
        int*   start  = (int*)(pcnt + N_GRAPHS);
        int*   cursor = start + (N_NODES + 1);
        int*   eid    = cursor + N_NODES;
        float* msg    = (float*)(eid + N_EDGES);
        float* h1     = msg + (size_t)N_EDGES*32;
        size_t zeroBytes = ((size_t)N_NODES + N_GRAPHS*32 + N_GRAPHS) * sizeof(float);

        hipMemsetAsync(d_ws, 0, zeroBytes, stream);

        build_deg_kernel<<<eg, eb, 0, stream>>>(tgts, deg);
        scan_deg_kernel<<<dim3(1), dim3(256), 0, stream>>>(deg, start, cursor);
        scatter_edges_kernel<<<eg, eb, 0, stream>>>(tgts, cursor, eid);

        edge_msg_kernel<<<eg, eb, 0, stream>>>(x, ea, srcs,
                                               en1_W1, en1_b1, en1_W2, en1_b2, msg);
        gather_update_eid_kernel<<<gg, gb, 0, stream>>>(x, msg, start, eid, root1, bias1,
                                                        h1, nullptr, nullptr, nullptr);
        edge_msg_kernel<<<eg, eb, 0, stream>>>(h1, ea, srcs,
                                               en2_W1, en2_b1, en2_W2, en2_b2, msg);
        gather_update_eid_kernel<<<gg, gb, 0, stream>>>(h1, msg, start, eid, root2, bias2,
                                                        nullptr, batch, pool, pcnt);

        head_kernel<<<dim3(1), dim3(64), 0, stream>>>(pool, pcnt, fcW, fcb, (float*)d_out);
    }
}

// Round 5
// 446.325 us; speedup vs baseline: 1.1281x; 1.1281x over previous
//
#include <hip/hip_runtime.h>

#define N_NODES   20000
#define N_EDGES   200000
#define NODE_DIM  32
#define EDGE_DIM  16
#define HIDDEN    32
#define N_GRAPHS  64
#define T_NODES   14   // src nodes per block; LDS = 14*1024*4 + 14*32*4*2 + 1024 = 61952 B

// ===========================================================================
// CSR build (tgt-CSR positions + src-CSR edge lists, fused passes)
// ===========================================================================

__global__ __launch_bounds__(256) void build_deg2_kernel(
    const int* __restrict__ tgts, const int* __restrict__ srcs,
    int* __restrict__ deg_t, int* __restrict__ deg_s)
{
    int e = blockIdx.x * blockDim.x + threadIdx.x;
    if (e >= N_EDGES) return;
    atomicAdd(deg_t + tgts[e], 1);
    atomicAdd(deg_s + srcs[e], 1);
}

__device__ void chunked_scan(const int* __restrict__ deg, int* __restrict__ start,
                             int* __restrict__ cursor, int* partial)
{
    const int C = (N_NODES + 255) / 256;   // 79
    int t  = threadIdx.x;
    int lo = t * C;
    int hi = lo + C < N_NODES ? lo + C : N_NODES;
    int s = 0;
    for (int i = lo; i < hi; ++i) s += deg[i];
    partial[t] = s;
    __syncthreads();
    if (t == 0) {
        int run = 0;
        for (int i = 0; i < 256; ++i) { int v = partial[i]; partial[i] = run; run += v; }
    }
    __syncthreads();
    int run = partial[t];
    for (int i = lo; i < hi; ++i) {
        start[i]  = run;
        cursor[i] = run;
        run += deg[i];
    }
    if (lo < N_NODES && hi == N_NODES) start[N_NODES] = run;
    __syncthreads();
}

__global__ __launch_bounds__(256) void scan2_kernel(
    const int* __restrict__ deg_t, int* __restrict__ start_t, int* __restrict__ cur_t,
    const int* __restrict__ deg_s, int* __restrict__ start_s, int* __restrict__ cur_s)
{
    __shared__ int partial[256];
    chunked_scan(deg_t, start_t, cur_t, partial);
    chunked_scan(deg_s, start_s, cur_s, partial);
}

// pos_t[e] = slot of edge e in tgt-order (msg written there -> gather is streaming)
__global__ __launch_bounds__(256) void scatter2_kernel(
    const int* __restrict__ tgts, const int* __restrict__ srcs,
    int* __restrict__ cur_t, int* __restrict__ cur_s,
    int* __restrict__ pos_t, int* __restrict__ eid_s)
{
    int e = blockIdx.x * blockDim.x + threadIdx.x;
    if (e >= N_EDGES) return;
    int p1 = atomicAdd(cur_t + tgts[e], 1);
    pos_t[e] = p1;
    int p2 = atomicAdd(cur_s + srcs[e], 1);
    eid_s[p2] = e;
}

// ===========================================================================
// src_conv: per block, T_NODES src nodes.
// Phase A: P[t][o][k^swz(o)] = sum_i x[t][i]*W2[k][i*32+o]   (XOR-swizzled k)
//          Q[t][o] = sum_i x[t][i]*b2[i*32+o]
// Phase B: per edge: lane kl computes h_kl, stages to H[slot][kl]; then
//          msg[pos_t[e]][o] = Q[s][o] + sum_kq dot4(H4(kq), P4[s][o][kq^swz])
//          -> 17 LDS wave-ops per edge-pair instead of 64.
// ===========================================================================
__global__ __launch_bounds__(256, 2) void src_conv_kernel(
    const float* __restrict__ feat,     // [N][32]
    const float* __restrict__ ea,       // [E][16]
    const int*   __restrict__ srcs,     // [E]
    const int*   __restrict__ start_s,  // [N+1]
    const int*   __restrict__ eid_s,    // [E]
    const int*   __restrict__ pos_t,    // [E]
    const float* __restrict__ W1,       // [16][32]
    const float* __restrict__ b1,       // [32]
    const float* __restrict__ W2,       // [32][1024]
    const float* __restrict__ b2,       // [1024]
    float*       __restrict__ msg)      // [E][32] in tgt-CSR order
{
    __shared__ __align__(16) float P[T_NODES][1024];   // [t][o*32 + (k^swz)]
    __shared__ __align__(16) float Q[T_NODES][32];
    __shared__ __align__(16) float XT[T_NODES][32];
    __shared__ __align__(16) float Hs[8][32];

    int tid = threadIdx.x;
    int v0  = blockIdx.x * T_NODES;
    int T_act = (N_NODES - v0) < T_NODES ? (N_NODES - v0) : T_NODES;

    // ---- stage x tile into LDS (clamped for tail block) ----
    if (tid < 8 * T_NODES) {
        int t  = tid >> 3;
        int og = tid & 7;
        int vv = v0 + t; if (vv > N_NODES - 1) vv = N_NODES - 1;
        float4 xx = *reinterpret_cast<const float4*>(feat + (size_t)vv * 32 + og * 4);
        *reinterpret_cast<float4*>(&XT[t][og * 4]) = xx;
    }
    __syncthreads();

    // ---- Phase A: P tile (thread = (k, og)) ----
    {
        int og = tid & 7;     // o = og*4 + c
        int k  = tid >> 3;    // 0..31
        float acc[T_NODES][4];
        #pragma unroll
        for (int t = 0; t < T_NODES; ++t) {
            acc[t][0] = 0.f; acc[t][1] = 0.f; acc[t][2] = 0.f; acc[t][3] = 0.f;
        }
        const float* w2p = W2 + (size_t)k * 1024 + og * 4;
        #pragma unroll
        for (int i = 0; i < 32; ++i) {
            float4 w4 = *reinterpret_cast<const float4*>(w2p + i * 32);
            #pragma unroll
            for (int t = 0; t < T_NODES; ++t) {
                float xv = XT[t][i];
                acc[t][0] += xv * w4.x; acc[t][1] += xv * w4.y;
                acc[t][2] += xv * w4.z; acc[t][3] += xv * w4.w;
            }
        }
        #pragma unroll
        for (int t = 0; t < T_NODES; ++t) {
            #pragma unroll
            for (int c = 0; c < 4; ++c) {
                int o = og * 4 + c;
                P[t][o * 32 + (k ^ ((o & 7) << 2))] = acc[t][c];
            }
        }
    }
    // ---- Q tile (threads 0..8*T_NODES-1) ----
    if (tid < 8 * T_NODES) {
        int t  = tid >> 3;
        int og = tid & 7;
        float q0 = 0.f, q1 = 0.f, q2 = 0.f, q3 = 0.f;
        const float* b2p = b2 + og * 4;
        #pragma unroll
        for (int i = 0; i < 32; ++i) {
            float4 b4 = *reinterpret_cast<const float4*>(b2p + i * 32);
            float xv = XT[t][i];
            q0 += xv * b4.x; q1 += xv * b4.y; q2 += xv * b4.z; q3 += xv * b4.w;
        }
        float4 qq; qq.x = q0; qq.y = q1; qq.z = q2; qq.w = q3;
        *reinterpret_cast<float4*>(&Q[t][og * 4]) = qq;
    }
    __syncthreads();

    // ---- Phase B: edges of this tile (contiguous src-CSR slice) ----
    int jb = start_s[v0];
    int je = start_s[v0 + T_act];
    int slot = tid >> 5;          // 0..7 (each wave owns 2 slots; no cross-wave LDS)
    int kl   = tid & 31;          // lane's k (for h) and o (for output)
    int sw   = (kl & 7) << 2;     // XOR swizzle for this lane's o

    float w1c[EDGE_DIM];
    #pragma unroll
    for (int j = 0; j < EDGE_DIM; ++j) w1c[j] = W1[j * 32 + kl];
    float b1v = b1[kl];

    for (int j0 = jb; j0 < je; j0 += 8) {
        int j = j0 + slot;
        if (j < je) {
            int e  = eid_s[j];
            int sl = srcs[e] - v0;
            int pr = pos_t[e];
            const float4* ea4 = reinterpret_cast<const float4*>(ea + (size_t)e * EDGE_DIM);
            float4 a0 = ea4[0], a1 = ea4[1], a2 = ea4[2], a3 = ea4[3];
            float hv = b1v;
            hv += a0.x * w1c[0]  + a0.y * w1c[1]  + a0.z * w1c[2]  + a0.w * w1c[3];
            hv += a1.x * w1c[4]  + a1.y * w1c[5]  + a1.z * w1c[6]  + a1.w * w1c[7];
            hv += a2.x * w1c[8]  + a2.y * w1c[9]  + a2.z * w1c[10] + a2.w * w1c[11];
            hv += a3.x * w1c[12] + a3.y * w1c[13] + a3.z * w1c[14] + a3.w * w1c[15];
            Hs[slot][kl] = fmaxf(hv, 0.f);     // intra-wave stage (same wave reads it)

            float accv = Q[sl][kl];
            const float* Pt = &P[sl][kl * 32];
            #pragma unroll
            for (int kq = 0; kq < 32; kq += 4) {
                float4 hq = *reinterpret_cast<const float4*>(&Hs[slot][kq]);     // broadcast
                float4 pq = *reinterpret_cast<const float4*>(&Pt[kq ^ sw]);      // swizzled
                accv += hq.x * pq.x + hq.y * pq.y + hq.z * pq.z + hq.w * pq.w;
            }
            msg[(size_t)pr * 32 + kl] = accv;
        }
    }
}

// ===========================================================================
// gather_update v2: msg in tgt-CSR order -> streaming segmented mean.
// 8 lanes per node; lane owns channel-quad c4 (float4 all the way).
// 4 independent accumulators force loads in flight (round-4 pathology fix).
// ===========================================================================
__global__ __launch_bounds__(256, 2) void gather_update_kernel(
    const float* __restrict__ feat,   // [N][32]
    const float* __restrict__ msg,    // [E][32] tgt-ordered
    const int*   __restrict__ start,  // [N+1] (tgt)
    const float* __restrict__ root,   // [32][32]
    const float* __restrict__ bias,   // [32]
    float*       __restrict__ outf,   // [N][32] or null
    const int*   __restrict__ batch,  // [N] or null
    float*       __restrict__ pool,   // [G][32]
    float*       __restrict__ pcnt)   // [G]
{
    int idx = blockIdx.x * blockDim.x + threadIdx.x;
    int v  = idx >> 3;
    int c4 = idx & 7;
    if (v >= N_NODES) return;

    int s0 = start[v], s1 = start[v + 1];
    const float4* m4 = reinterpret_cast<const float4*>(msg);   // [E][8]

    float4 a0 = {0.f,0.f,0.f,0.f}, a1 = {0.f,0.f,0.f,0.f};
    float4 a2 = {0.f,0.f,0.f,0.f}, a3 = {0.f,0.f,0.f,0.f};
    int j = s0;
    for (; j + 4 <= s1; j += 4) {
        float4 t0 = m4[(size_t)(j + 0) * 8 + c4];
        float4 t1 = m4[(size_t)(j + 1) * 8 + c4];
        float4 t2 = m4[(size_t)(j + 2) * 8 + c4];
        float4 t3 = m4[(size_t)(j + 3) * 8 + c4];
        a0.x += t0.x; a0.y += t0.y; a0.z += t0.z; a0.w += t0.w;
        a1.x += t1.x; a1.y += t1.y; a1.z += t1.z; a1.w += t1.w;
        a2.x += t2.x; a2.y += t2.y; a2.z += t2.z; a2.w += t2.w;
        a3.x += t3.x; a3.y += t3.y; a3.z += t3.z; a3.w += t3.w;
    }
    for (; j < s1; ++j) {
        float4 t = m4[(size_t)j * 8 + c4];
        a0.x += t.x; a0.y += t.y; a0.z += t.z; a0.w += t.w;
    }
    float sx = (a0.x + a1.x) + (a2.x + a3.x);
    float sy = (a0.y + a1.y) + (a2.y + a3.y);
    float sz = (a0.z + a1.z) + (a2.z + a3.z);
    float sw_ = (a0.w + a1.w) + (a2.w + a3.w);

    int d = s1 - s0;
    float invd = 1.0f / (float)(d > 0 ? d : 1);
    float4 bb = *reinterpret_cast<const float4*>(bias + c4 * 4);
    float ax = sx * invd + bb.x;
    float ay = sy * invd + bb.y;
    float az = sz * invd + bb.z;
    float aw = sw_ * invd + bb.w;

    // root GEMM: channels c4*4..+3
    const float*  xv = feat + (size_t)v * 32;
    const float4* r4 = reinterpret_cast<const float4*>(root);  // [32][8]
    #pragma unroll
    for (int i = 0; i < 32; ++i) {
        float  xi = xv[i];
        float4 rr = r4[i * 8 + c4];
        ax += xi * rr.x; ay += xi * rr.y; az += xi * rr.z; aw += xi * rr.w;
    }
    ax = fmaxf(ax, 0.f); ay = fmaxf(ay, 0.f); az = fmaxf(az, 0.f); aw = fmaxf(aw, 0.f);

    if (outf) {
        float4 t; t.x = ax; t.y = ay; t.z = az; t.w = aw;
        *reinterpret_cast<float4*>(outf + (size_t)v * 32 + c4 * 4) = t;
    }
    if (batch) {
        int g = batch[v];
        float* p = pool + (size_t)g * 32 + c4 * 4;
        atomicAdd(p + 0, ax); atomicAdd(p + 1, ay);
        atomicAdd(p + 2, az); atomicAdd(p + 3, aw);
        if (c4 == 0) atomicAdd(pcnt + g, 1.0f);
    }
}

__global__ void head_kernel(
    const float* __restrict__ pool, const float* __restrict__ pcnt,
    const float* __restrict__ fcW, const float* __restrict__ fcb,
    float* __restrict__ out)
{
    int g = threadIdx.x;
    if (g >= N_GRAPHS) return;
    float inv = 1.0f / fmaxf(pcnt[g], 1.0f);
    float o0 = fcb[0], o1 = fcb[1];
    #pragma unroll
    for (int i = 0; i < 32; ++i) {
        float m = pool[g * 32 + i] * inv;
        o0 += m * fcW[i * 2 + 0];
        o1 += m * fcW[i * 2 + 1];
    }
    out[g * 2 + 0] = o0;
    out[g * 2 + 1] = o1;
}

// ===========================================================================
// Fallback (round-2 proven path) if ws too small
// ===========================================================================
__global__ __launch_bounds__(256) void build_deg_kernel(
    const int* __restrict__ tgts, int* __restrict__ deg)
{
    int e = blockIdx.x * blockDim.x + threadIdx.x;
    if (e >= N_EDGES) return;
    atomicAdd(deg + tgts[e], 1);
}

__global__ __launch_bounds__(256) void scan_deg_kernel(
    const int* __restrict__ deg, int* __restrict__ start, int* __restrict__ cursor)
{
    __shared__ int partial[256];
    chunked_scan(deg, start, cursor, partial);
}

__global__ __launch_bounds__(256) void scatter_edges_kernel(
    const int* __restrict__ tgts, int* __restrict__ cursor, int* __restrict__ eid)
{
    int e = blockIdx.x * blockDim.x + threadIdx.x;
    if (e >= N_EDGES) return;
    int pos = atomicAdd(cursor + tgts[e], 1);
    eid[pos] = e;
}

__global__ __launch_bounds__(256) void edge_msg_kernel(
    const float* __restrict__ feat, const float* __restrict__ ea,
    const int* __restrict__ srcs,
    const float* __restrict__ W1, const float* __restrict__ b1,
    const float* __restrict__ W2, const float* __restrict__ b2,
    float* __restrict__ msg)
{
    int e = blockIdx.x * blockDim.x + threadIdx.x;
    if (e >= N_EDGES) return;
    float a[EDGE_DIM];
    const float4* ea4 = reinterpret_cast<const float4*>(ea + (size_t)e * EDGE_DIM);
    #pragma unroll
    for (int q = 0; q < EDGE_DIM / 4; ++q) {
        float4 t = ea4[q];
        a[q*4+0] = t.x; a[q*4+1] = t.y; a[q*4+2] = t.z; a[q*4+3] = t.w;
    }
    int s = srcs[e];
    float x[32];
    const float4* x4 = reinterpret_cast<const float4*>(feat + (size_t)s * 32);
    #pragma unroll
    for (int q = 0; q < 8; ++q) {
        float4 t = x4[q];
        x[q*4+0] = t.x; x[q*4+1] = t.y; x[q*4+2] = t.z; x[q*4+3] = t.w;
    }
    float acc[32];
    #pragma unroll
    for (int o = 0; o < 32; ++o) acc[o] = 0.0f;
    #pragma unroll
    for (int i = 0; i < 32; ++i) {
        float xi = x[i];
        #pragma unroll
        for (int o = 0; o < 32; ++o) acc[o] += xi * b2[i*32+o];
    }
    for (int k = 0; k < 32; ++k) {
        float hk = b1[k];
        #pragma unroll
        for (int j = 0; j < EDGE_DIM; ++j) hk += a[j] * W1[j*32 + k];
        hk = fmaxf(hk, 0.0f);
        const float* w = W2 + (size_t)k * 1024;
        #pragma unroll
        for (int i = 0; i < 32; ++i) {
            float c = hk * x[i];
            #pragma unroll
            for (int o = 0; o < 32; ++o) acc[o] += c * w[i*32+o];
        }
    }
    float4* m4 = reinterpret_cast<float4*>(msg + (size_t)e * 32);
    #pragma unroll
    for (int q = 0; q < 8; ++q) {
        float4 t;
        t.x = acc[q*4+0]; t.y = acc[q*4+1]; t.z = acc[q*4+2]; t.w = acc[q*4+3];
        m4[q] = t;
    }
}

__global__ __launch_bounds__(256) void gather_update_eid_kernel(
    const float* __restrict__ feat, const float* __restrict__ msg,
    const int* __restrict__ start, const int* __restrict__ eid,
    const float* __restrict__ root, const float* __restrict__ bias,
    float* __restrict__ outf, const int* __restrict__ batch,
    float* __restrict__ pool, float* __restrict__ pcnt)
{
    int idx = blockIdx.x * blockDim.x + threadIdx.x;
    int v = idx >> 5;
    int o = idx & 31;
    if (v >= N_NODES) return;
    int s0 = start[v], s1 = start[v + 1];
    float sum = 0.0f;
    for (int j = s0; j < s1; ++j) {
        int e = eid[j];
        sum += msg[(size_t)e * 32 + o];
    }
    int d = s1 - s0;
    float acc = sum / (float)(d > 0 ? d : 1) + bias[o];
    const float* xv = feat + (size_t)v * 32;
    #pragma unroll
    for (int i = 0; i < 32; ++i) acc += xv[i] * root[i * 32 + o];
    acc = fmaxf(acc, 0.0f);
    if (outf) outf[(size_t)v * 32 + o] = acc;
    if (batch) {
        int g = batch[v];
        atomicAdd(pool + (size_t)g * 32 + o, acc);
        if (o == 0) atomicAdd(pcnt + g, 1.0f);
    }
}

// ===========================================================================

extern "C" void kernel_launch(void* const* d_in, const int* in_sizes, int n_in,
                              void* d_out, int out_size, void* d_ws, size_t ws_size,
                              hipStream_t stream)
{
    const float* x      = (const float*)d_in[0];
    const float* ea     = (const float*)d_in[1];
    const int*   ei     = (const int*)d_in[2];   // [2][E]
    const int*   batch  = (const int*)d_in[3];
    const float* en1_W1 = (const float*)d_in[4];
    const float* en1_b1 = (const float*)d_in[5];
    const float* en1_W2 = (const float*)d_in[6];
    const float* en1_b2 = (const float*)d_in[7];
    const float* root1  = (const float*)d_in[8];
    const float* bias1  = (const float*)d_in[9];
    const float* en2_W1 = (const float*)d_in[10];
    const float* en2_b1 = (const float*)d_in[11];
    const float* en2_W2 = (const float*)d_in[12];
    const float* en2_b2 = (const float*)d_in[13];
    const float* root2  = (const float*)d_in[14];
    const float* bias2  = (const float*)d_in[15];
    const float* fcW    = (const float*)d_in[16];
    const float* fcb    = (const float*)d_in[17];

    const int* srcs = ei;
    const int* tgts = ei + N_EDGES;

    dim3 eb(256), eg((N_EDGES + 255) / 256);
    dim3 gb(256), gg((N_NODES * 8 + 255) / 256);
    const int NBLK = (N_NODES + T_NODES - 1) / T_NODES;

    size_t need_new = (size_t)2*N_NODES + N_GRAPHS*32 + N_GRAPHS
                    + 2*(N_NODES + 2) + 2*N_NODES + 2*(size_t)N_EDGES
                    + (size_t)N_EDGES*32 + (size_t)N_NODES*32;

    if (ws_size >= need_new * sizeof(float)) {
        int*   deg_t   = (int*)d_ws;
        int*   deg_s   = deg_t + N_NODES;
        float* pool    = (float*)(deg_s + N_NODES);
        float* pcnt    = pool + (size_t)N_GRAPHS*32;
        int*   start_t = (int*)(pcnt + N_GRAPHS);
        int*   cur_t   = start_t + (N_NODES + 2);
        int*   pos_t   = cur_t + N_NODES;
        int*   start_s = pos_t + N_EDGES;
        int*   cur_s   = start_s + (N_NODES + 2);
        int*   eid_s   = cur_s + N_NODES;
        float* msg     = (float*)(eid_s + N_EDGES);
        float* h1      = msg + (size_t)N_EDGES*32;
        size_t zeroBytes = ((size_t)2*N_NODES + N_GRAPHS*32 + N_GRAPHS) * sizeof(float);

        hipMemsetAsync(d_ws, 0, zeroBytes, stream);

        build_deg2_kernel<<<eg, eb, 0, stream>>>(tgts, srcs, deg_t, deg_s);
        scan2_kernel<<<dim3(1), dim3(256), 0, stream>>>(deg_t, start_t, cur_t,
                                                        deg_s, start_s, cur_s);
        scatter2_kernel<<<eg, eb, 0, stream>>>(tgts, srcs, cur_t, cur_s, pos_t, eid_s);

        // conv1
        src_conv_kernel<<<dim3(NBLK), dim3(256), 0, stream>>>(
            x, ea, srcs, start_s, eid_s, pos_t, en1_W1, en1_b1, en1_W2, en1_b2, msg);
        gather_update_kernel<<<gg, gb, 0, stream>>>(x, msg, start_t, root1, bias1,
                                                    h1, nullptr, nullptr, nullptr);
        // conv2
        src_conv_kernel<<<dim3(NBLK), dim3(256), 0, stream>>>(
            h1, ea, srcs, start_s, eid_s, pos_t, en2_W1, en2_b1, en2_W2, en2_b2, msg);
        gather_update_kernel<<<gg, gb, 0, stream>>>(h1, msg, start_t, root2, bias2,
                                                    nullptr, batch, pool, pcnt);

        head_kernel<<<dim3(1), dim3(64), 0, stream>>>(pool, pcnt, fcW, fcb, (float*)d_out);
    } else {
        // round-2 proven fallback
        int*   deg    = (int*)d_ws;
        float* pool   = (float*)(deg + N_NODES);
        float* pcnt   = pool + (size_t)N_GRAPHS*32;
        int*   start  = (int*)(pcnt + N_GRAPHS);
        int*   cursor = start + (N_NODES + 1);
        int*   eid    = cursor + N_NODES;
        float* msg    = (float*)(eid + N_EDGES);
        float* h1     = msg + (size_t)N_EDGES*32;
        size_t zeroBytes = ((size_t)N_NODES + N_GRAPHS*32 + N_GRAPHS) * sizeof(float);

        hipMemsetAsync(d_ws, 0, zeroBytes, stream);

        dim3 gg32((N_NODES * 32 + 255) / 256);
        build_deg_kernel<<<eg, eb, 0, stream>>>(tgts, deg);
        scan_deg_kernel<<<dim3(1), dim3(256), 0, stream>>>(deg, start, cursor);
        scatter_edges_kernel<<<eg, eb, 0, stream>>>(tgts, cursor, eid);

        edge_msg_kernel<<<eg, eb, 0, stream>>>(x, ea, srcs,
                                               en1_W1, en1_b1, en1_W2, en1_b2, msg);
        gather_update_eid_kernel<<<gg32, gb, 0, stream>>>(x, msg, start, eid, root1, bias1,
                                                          h1, nullptr, nullptr, nullptr);
        edge_msg_kernel<<<eg, eb, 0, stream>>>(h1, ea, srcs,
                                               en2_W1, en2_b1, en2_W2, en2_b2, msg);
        edge_msg_kernel<<<eg, eb, 0, stream>>>(h1, ea, srcs,
                                               en2_W1, en2_b1, en2_W2, en2_b2, msg);
        gather_update_eid_kernel<<<gg32, gb, 0, stream>>>(h1, msg, start, eid, root2, bias2,
                                                          nullptr, batch, pool, pcnt);
        head_kernel<<<dim3(1), dim3(64), 0, stream>>>(pool, pcnt, fcW, fcb, (float*)d_out);
    }
}